// Round 13
// baseline (175.900 us; speedup 1.0000x reference)
//
#include <hip/hip_runtime.h>

typedef __bf16 bf16_t;
typedef __bf16 bf16x8 __attribute__((ext_vector_type(8)));
typedef float f32x4 __attribute__((ext_vector_type(4)));

#define BK 64
#define NNODES 24576

// ws layout (bytes):
//   0        W1b   (512*512 bf16)  = 524288
//   524288   W2t   (512*512 bf16)  = 524288
//   1048576  W4t   (512*1536 bf16) = 1572864
//   2621440  Wct   (512*512 bf16)  = 524288
//   3145728  bc    (512 f32)       = 2048
//   3147776  u     (512 f32)       = 2048
//   3149824  c3    (3*24576 f32)   = 294912
//   3444736  sbuf  (24576 f32)     = 98304
//   3543040  G2    (24576*512 bf16)= 25165824  [Wctp (4MB f32) overlaps G2 head:
//            consumed by wct_reduce BEFORE the G-GEMM writes G2]
// d_out chunk0 (48MB f32 xbo, dead until final GEMM):
//   0        Xb    (24576*512 bf16)= 25165824

__device__ __forceinline__ void g2l16(const void* g, void* l) {
    __builtin_amdgcn_global_load_lds((__attribute__((address_space(1))) void*)(g),
                                     (__attribute__((address_space(3))) void*)(l),
                                     16, 0, 0);
}

#define SB()  __builtin_amdgcn_sched_barrier(0)
#define BAR() __builtin_amdgcn_s_barrier()

// ============ 16-wave GEMM: tile 192x256, BK=64, 1024 threads (R9 core) ====
// mode 0: bf16 store; mode 1: f32 silu store;
// mode 3: G-epilogue — G2[r,c]=bf16(g^2), s[r] += g.W3 (atomic)
__global__ __launch_bounds__(1024)
void gemm16_kernel(const bf16_t* __restrict__ A, const bf16_t* __restrict__ Bt,
                   const float* __restrict__ bias, void* __restrict__ Cout,
                   int N, int K, int mode,
                   const float* __restrict__ W3, float* __restrict__ sbuf)
{
    __shared__ __align__(16) bf16_t lA[2][12288];   // 192 rows x 128B per buf
    __shared__ __align__(16) bf16_t lB[2][16384];   // 256 rows x 128B per buf

    const int tid  = threadIdx.x;
    const int lane = tid & 63;
    const int wave = tid >> 6;       // 0..15
    const int wr   = wave >> 2;      // 0..3
    const int wc   = wave & 3;       // 0..3
    const int l15  = lane & 15;
    const int lh   = lane >> 4;      // 0..3

    const int bm = blockIdx.x;
    const int bn = blockIdx.y;

    const size_t strb = (size_t)K * 2;

    const int q0 = tid * 16;
    const size_t ro = (size_t)(q0 >> 7) * strb + ((q0 ^ (((q0 >> 7) & 7) << 4)) & 127);
    const char* gA = (const char*)A  + (size_t)bm * 192 * strb + ro;
    const char* gB = (const char*)Bt + (size_t)bn * 256 * strb + ro;
    char* baseA = (char*)&lA[0][0];
    char* baseB = (char*)&lB[0][0];

    auto stage = [&](int t, int buf) {
        const size_t kb = (size_t)t * 128;
        g2l16(gA + kb, baseA + buf * 24576 + q0);
        if (tid < 512)
            g2l16(gA + kb + 128 * strb, baseA + buf * 24576 + 16384 + q0);
        g2l16(gB + kb, baseB + buf * 32768 + q0);
        g2l16(gB + kb + 128 * strb, baseB + buf * 32768 + 16384 + q0);
    };

    const int swzr = (l15 & 7) << 4;
    const int xk0  = (lh * 16) ^ swzr;
    const int xk1  = (64 + lh * 16) ^ swzr;
    const int aOff = (wr * 48 + l15) * 128;
    const int bOff = (wc * 64 + l15) * 128;

    f32x4 acc[3][4] = {};

    const int T = K / BK;
    stage(0, 0);

    for (int t = 0; t < T; ++t) {
        const int buf = t & 1;

        asm volatile("s_waitcnt vmcnt(0)" ::: "memory");
        BAR();
        SB();

        if (t + 1 < T) stage(t + 1, buf ^ 1);
        SB();

        bf16x8 af[3][2], bf[4][2];
        {
            const char* _pa = baseA + buf * 24576 + aOff;
#pragma unroll
            for (int m = 0; m < 3; ++m) {
                af[m][0] = *(const bf16x8*)(_pa + m * 2048 + xk0);
                af[m][1] = *(const bf16x8*)(_pa + m * 2048 + xk1);
            }
            const char* _pb = baseB + buf * 32768 + bOff;
#pragma unroll
            for (int n = 0; n < 4; ++n) {
                bf[n][0] = *(const bf16x8*)(_pb + n * 2048 + xk0);
                bf[n][1] = *(const bf16x8*)(_pb + n * 2048 + xk1);
            }
        }

        __builtin_amdgcn_s_setprio(1);
#pragma unroll
        for (int m = 0; m < 3; ++m)
#pragma unroll
        for (int n = 0; n < 4; ++n)
#pragma unroll
        for (int kk = 0; kk < 2; ++kk)
            acc[m][n] = __builtin_amdgcn_mfma_f32_16x16x32_bf16(
                af[m][kk], bf[n][kk], acc[m][n], 0, 0, 0);
        __builtin_amdgcn_s_setprio(0);
    }

    // C/D frag layout: col = lane&15, row = (lane>>4)*4 + j
    const int gr0 = bm * 192 + wr * 48 + lh * 4;
    const int gc0 = bn * 256 + wc * 64 + l15;
    if (mode == 0) {
        bf16_t* C = (bf16_t*)Cout;
#pragma unroll
        for (int m = 0; m < 3; ++m)
#pragma unroll
        for (int n = 0; n < 4; ++n) {
            const int c = gc0 + n * 16;
            const float bv = bias ? bias[c] : 0.f;
#pragma unroll
            for (int j = 0; j < 4; ++j)
                C[(size_t)(gr0 + m * 16 + j) * N + c] = (bf16_t)(acc[m][n][j] + bv);
        }
    } else if (mode == 1) {
        float* C = (float*)Cout;
#pragma unroll
        for (int m = 0; m < 3; ++m)
#pragma unroll
        for (int n = 0; n < 4; ++n) {
            const int c = gc0 + n * 16;
            const float bv = bias[c];
#pragma unroll
            for (int j = 0; j < 4; ++j) {
                float v = acc[m][n][j] + bv;
                C[(size_t)(gr0 + m * 16 + j) * N + c] = v / (1.f + __expf(-v));
            }
        }
    } else {
        // mode 3: fused G epilogue -> G2 = bf16(g^2), s[r] += g.W3
        bf16_t* G2 = (bf16_t*)Cout;
        float w3v[4], bv[4];
#pragma unroll
        for (int n = 0; n < 4; ++n) {
            w3v[n] = W3[gc0 + n * 16];
            bv[n]  = bias[gc0 + n * 16];
        }
#pragma unroll
        for (int m = 0; m < 3; ++m)
#pragma unroll
        for (int j = 0; j < 4; ++j) {
            const int r = gr0 + m * 16 + j;
            float g[4], p = 0.f;
#pragma unroll
            for (int n = 0; n < 4; ++n) {
                g[n] = acc[m][n][j] + bv[n];
                p += g[n] * w3v[n];
            }
            // reduce across the 16 l15-lanes (same row, different cols; lh constant)
            p += __shfl_xor(p, 1); p += __shfl_xor(p, 2);
            p += __shfl_xor(p, 4); p += __shfl_xor(p, 8);
            if (l15 == 0) atomicAdd(&sbuf[r], p);
            bf16_t* grow = G2 + (size_t)r * 512 + gc0;
#pragma unroll
            for (int n = 0; n < 4; ++n)
                grow[n * 16] = (bf16_t)(g[n] * g[n]);
        }
    }
}

// ============ final GEMM: xbo = silu( sum_l c_l * (G2 @ W4_l) + b4 ) =======
// A = G2 (24576x512), staged 3x (once per W4 K-segment, L2/L3-hot on 2nd/3rd);
// c_l folded into the accumulator via telescoping rescale at segment bounds:
//   acc=Y0; *= c0/c1; +=Y1; *= c1/c2; +=Y2; *= c2  (denoms clamped 1e-30).
__global__ __launch_bounds__(1024)
void gemm16f_kernel(const bf16_t* __restrict__ G2, const bf16_t* __restrict__ W4t,
                    const float* __restrict__ b4, const float* __restrict__ c3v,
                    float* __restrict__ xbo)
{
    __shared__ __align__(16) bf16_t lA[2][12288];
    __shared__ __align__(16) bf16_t lB[2][16384];

    const int tid  = threadIdx.x;
    const int lane = tid & 63;
    const int wave = tid >> 6;
    const int wr   = wave >> 2;
    const int wc   = wave & 3;
    const int l15  = lane & 15;
    const int lh   = lane >> 4;

    const int bm = blockIdx.x;
    const int bn = blockIdx.y;

    const size_t strbA = 1024;   // 512 elems * 2B
    const size_t strbB = 3072;   // 1536 elems * 2B

    const int q0 = tid * 16;
    const int qx = (q0 ^ (((q0 >> 7) & 7) << 4)) & 127;
    const size_t roA = (size_t)(q0 >> 7) * strbA + qx;
    const size_t roB = (size_t)(q0 >> 7) * strbB + qx;
    const char* gA = (const char*)G2  + (size_t)bm * 192 * strbA + roA;
    const char* gB = (const char*)W4t + (size_t)bn * 256 * strbB + roB;
    char* baseA = (char*)&lA[0][0];
    char* baseB = (char*)&lB[0][0];

    auto stage = [&](int tt, int buf) {
        const size_t kbA = (size_t)(tt & 7) * 128;   // A K-tile repeats per segment
        const size_t kbB = (size_t)tt * 128;         // B runs through full K=1536
        g2l16(gA + kbA, baseA + buf * 24576 + q0);
        if (tid < 512)
            g2l16(gA + kbA + 128 * strbA, baseA + buf * 24576 + 16384 + q0);
        g2l16(gB + kbB, baseB + buf * 32768 + q0);
        g2l16(gB + kbB + 128 * strbB, baseB + buf * 32768 + 16384 + q0);
    };

    const int swzr = (l15 & 7) << 4;
    const int xk0  = (lh * 16) ^ swzr;
    const int xk1  = (64 + lh * 16) ^ swzr;
    const int aOff = (wr * 48 + l15) * 128;
    const int bOff = (wc * 64 + l15) * 128;

    const int gr0 = bm * 192 + wr * 48 + lh * 4;
    const int gc0 = bn * 256 + wc * 64 + l15;

    f32x4 acc[3][4] = {};

    stage(0, 0);

    for (int tt = 0; tt < 24; ++tt) {
        const int buf = tt & 1;

        asm volatile("s_waitcnt vmcnt(0)" ::: "memory");
        BAR();
        SB();

        if (tt + 1 < 24) stage(tt + 1, buf ^ 1);
        SB();

        bf16x8 af[3][2], bf[4][2];
        {
            const char* _pa = baseA + buf * 24576 + aOff;
#pragma unroll
            for (int m = 0; m < 3; ++m) {
                af[m][0] = *(const bf16x8*)(_pa + m * 2048 + xk0);
                af[m][1] = *(const bf16x8*)(_pa + m * 2048 + xk1);
            }
            const char* _pb = baseB + buf * 32768 + bOff;
#pragma unroll
            for (int n = 0; n < 4; ++n) {
                bf[n][0] = *(const bf16x8*)(_pb + n * 2048 + xk0);
                bf[n][1] = *(const bf16x8*)(_pb + n * 2048 + xk1);
            }
        }

        __builtin_amdgcn_s_setprio(1);
#pragma unroll
        for (int m = 0; m < 3; ++m)
#pragma unroll
        for (int n = 0; n < 4; ++n)
#pragma unroll
        for (int kk = 0; kk < 2; ++kk)
            acc[m][n] = __builtin_amdgcn_mfma_f32_16x16x32_bf16(
                af[m][kk], bf[n][kk], acc[m][n], 0, 0, 0);
        __builtin_amdgcn_s_setprio(0);

        // segment-boundary accumulator rescale
        if (tt == 7) {
#pragma unroll
            for (int m = 0; m < 3; ++m)
#pragma unroll
            for (int j = 0; j < 4; ++j) {
                const int r = gr0 + m * 16 + j;
                const float ra = c3v[r] / fmaxf(c3v[r + NNODES], 1e-30f);
#pragma unroll
                for (int n = 0; n < 4; ++n) acc[m][n][j] *= ra;
            }
        } else if (tt == 15) {
#pragma unroll
            for (int m = 0; m < 3; ++m)
#pragma unroll
            for (int j = 0; j < 4; ++j) {
                const int r = gr0 + m * 16 + j;
                const float ra = fmaxf(c3v[r + NNODES], 1e-30f)
                               / fmaxf(c3v[r + 2 * NNODES], 1e-30f);
#pragma unroll
                for (int n = 0; n < 4; ++n) acc[m][n][j] *= ra;
            }
        }
    }

    // epilogue: v = acc*c2 + b4 ; silu ; f32 store
#pragma unroll
    for (int m = 0; m < 3; ++m)
#pragma unroll
    for (int j = 0; j < 4; ++j) {
        const int r = gr0 + m * 16 + j;
        const float c2 = fmaxf(c3v[r + 2 * NNODES], 1e-30f);
        float* xrow = xbo + (size_t)r * 512;
#pragma unroll
        for (int n = 0; n < 4; ++n) {
            const int c = gc0 + n * 16;
            float v = acc[m][n][j] * c2 + b4[c];
            xrow[c] = v / (1.f + __expf(-v));
        }
    }
}

// ============ 8-wave GEMM (split-K) — Wct partials only ============
__global__ __launch_bounds__(512)
void gemm8_kernel(const bf16_t* __restrict__ A, const bf16_t* __restrict__ Bt,
                  void* __restrict__ Cout, int N, int K, int LD)
{
    __shared__ __align__(16) bf16_t lA[2][16384];
    __shared__ __align__(16) bf16_t lB[2][16384];

    const int tid  = threadIdx.x;
    const int lane = tid & 63;
    const int wave = tid >> 6;
    const int wr   = wave >> 2;
    const int wc   = wave & 3;
    const int l15  = lane & 15;
    const int lh   = lane >> 4;

    const int bm = blockIdx.x;
    const int bn = blockIdx.y;
    const int bz = blockIdx.z;

    const size_t strb = (size_t)LD * 2;
    const size_t zoff = (size_t)bz * K * 2;

    const int q0 = tid * 16;
    const size_t rowOff = (size_t)(q0 >> 7) * strb + ((q0 ^ (((q0 >> 7) & 7) << 4)) & 127);
    const char* gA = (const char*)A  + (size_t)bm * 256 * strb + zoff + rowOff;
    const char* gB = (const char*)Bt + (size_t)bn * 256 * strb + zoff + rowOff;
    char* baseA = (char*)&lA[0][0];
    char* baseB = (char*)&lB[0][0];

    auto stageA = [&](int t, int buf, int r) {
        g2l16(gA + (size_t)t * 128 + (size_t)(r * 64) * strb,
              baseA + buf * 32768 + r * 8192 + q0);
    };
    auto stageB = [&](int t, int buf, int r) {
        g2l16(gB + (size_t)t * 128 + (size_t)(r * 64) * strb,
              baseB + buf * 32768 + r * 8192 + q0);
    };

    const int swzr = (l15 & 7) << 4;
    const int xk0  = (lh * 16) ^ swzr;
    const int xk1  = (64 + lh * 16) ^ swzr;
    const int aOff = wr * 16384 + l15 * 128;
    const int bOff = wc * 8192 + l15 * 128;

    f32x4 acc[2][2][4][2] = {};

    const int T = K / BK;

#pragma unroll
    for (int r = 0; r < 4; ++r) { stageA(0, 0, r); stageB(0, 0, r); }

    for (int t = 0; t < T; ++t) {
        const int buf = t & 1, nbuf = buf ^ 1;

        asm volatile("s_waitcnt vmcnt(0)" ::: "memory");
        BAR();
        SB();

        if (t + 1 < T) {
#pragma unroll
            for (int r = 0; r < 4; ++r) { stageA(t + 1, nbuf, r); stageB(t + 1, nbuf, r); }
        }
        SB();

        bf16x8 af[8][2], bf[4][2];
        {
            const char* _pa = baseA + buf * 32768 + aOff;
#pragma unroll
            for (int i = 0; i < 8; ++i) {
                af[i][0] = *(const bf16x8*)(_pa + i * 2048 + xk0);
                af[i][1] = *(const bf16x8*)(_pa + i * 2048 + xk1);
            }
            const char* _pb = baseB + buf * 32768 + bOff;
#pragma unroll
            for (int j = 0; j < 4; ++j) {
                bf[j][0] = *(const bf16x8*)(_pb + j * 2048 + xk0);
                bf[j][1] = *(const bf16x8*)(_pb + j * 2048 + xk1);
            }
        }

        __builtin_amdgcn_s_setprio(1);
#pragma unroll
        for (int mh = 0; mh < 2; ++mh)
#pragma unroll
        for (int nh = 0; nh < 2; ++nh)
#pragma unroll
        for (int m = 0; m < 4; ++m)
#pragma unroll
        for (int n = 0; n < 2; ++n)
#pragma unroll
        for (int kk = 0; kk < 2; ++kk)
            acc[mh][nh][m][n] = __builtin_amdgcn_mfma_f32_16x16x32_bf16(
                af[mh * 4 + m][kk], bf[nh * 2 + n][kk], acc[mh][nh][m][n], 0, 0, 0);
        __builtin_amdgcn_s_setprio(0);
    }

    float* C = (float*)Cout + (size_t)bz * 512 * 512;
    const int gr0 = bm * 256 + wr * 128 + lh * 4;
    const int gc0 = bn * 256 + wc * 64 + l15;
#pragma unroll
    for (int mh = 0; mh < 2; ++mh)
#pragma unroll
    for (int nh = 0; nh < 2; ++nh)
#pragma unroll
    for (int m = 0; m < 4; ++m)
#pragma unroll
    for (int n = 0; n < 2; ++n) {
        const int c = gc0 + nh * 32 + n * 16;
#pragma unroll
        for (int j = 0; j < 4; ++j)
            C[(size_t)(gr0 + (mh * 4 + m) * 16 + j) * N + c] = acc[mh][nh][m][n][j];
    }
}

__global__ void wct_reduce_kernel(const float* __restrict__ p, bf16_t* __restrict__ out) {
    const int i = blockIdx.x * 256 + threadIdx.x;   // < 262144
    out[i] = (bf16_t)(p[i] + p[i + 262144] + p[i + 524288] + p[i + 786432]);
}

__global__ void cast8_kernel(const float* __restrict__ in, bf16_t* __restrict__ out, int n8) {
    const int i = blockIdx.x * blockDim.x + threadIdx.x;
    if (i >= n8) return;
    const float4* pp = (const float4*)in + (size_t)i * 2;
    float4 a = pp[0], b = pp[1];
    bf16x8 v;
    v[0] = (bf16_t)a.x; v[1] = (bf16_t)a.y; v[2] = (bf16_t)a.z; v[3] = (bf16_t)a.w;
    v[4] = (bf16_t)b.x; v[5] = (bf16_t)b.y; v[6] = (bf16_t)b.z; v[7] = (bf16_t)b.w;
    *(bf16x8*)(out + (size_t)i * 8) = v;
}

// fused weight prep: [0,128) cast W1; [128,1152) transpose W2; [1152,4224) transpose W4
__global__ void prep_kernel(const float* __restrict__ W1, bf16_t* __restrict__ W1b,
                            const float* __restrict__ W2, bf16_t* __restrict__ W2t,
                            const float* __restrict__ W4, bf16_t* __restrict__ W4t)
{
    const int b = blockIdx.x;
    if (b < 128) {
        const int i = b * 256 + threadIdx.x;
        const float4* p = (const float4*)W1 + (size_t)i * 2;
        float4 a = p[0], c = p[1];
        bf16x8 v;
        v[0] = (bf16_t)a.x; v[1] = (bf16_t)a.y; v[2] = (bf16_t)a.z; v[3] = (bf16_t)a.w;
        v[4] = (bf16_t)c.x; v[5] = (bf16_t)c.y; v[6] = (bf16_t)c.z; v[7] = (bf16_t)c.w;
        *(bf16x8*)(W1b + (size_t)i * 8) = v;
    } else if (b < 1152) {
        const int idx = (b - 128) * 256 + threadIdx.x;
        const int c = idx >> 9, r = idx & 511;
        W2t[idx] = (bf16_t)W2[(size_t)r * 512 + c];
    } else {
        const int idx = (b - 1152) * 256 + threadIdx.x;
        const int c = idx / 1536, r = idx - c * 1536;
        W4t[idx] = (bf16_t)W4[(size_t)r * 512 + c];
    }
}

// u[t] = sum_i v[i] * W[i][t]
__global__ void vecmat_kernel(const float* __restrict__ v, const float* __restrict__ W,
                              float* __restrict__ out) {
    const int t = blockIdx.x * blockDim.x + threadIdx.x;
    if (t >= 512) return;
    float s = 0.f;
    for (int i = 0; i < 512; ++i) s += v[i] * W[i * 512 + t];
    out[t] = s;
}

// c3[l][n] = sum_{m in seg l} chi[n,m]^2
__global__ void c3_kernel(const float* __restrict__ chi, float* __restrict__ c3) {
    const int n = blockIdx.x * 256 + threadIdx.x;
    if (n >= NNODES) return;
    const float* ch = chi + (size_t)n * 15;
    float a = 0.f, b = 0.f, c = 0.f;
#pragma unroll
    for (int m = 0; m < 3; ++m)  a += ch[m] * ch[m];
#pragma unroll
    for (int m = 3; m < 8; ++m)  b += ch[m] * ch[m];
#pragma unroll
    for (int m = 8; m < 15; ++m) c += ch[m] * ch[m];
    c3[n] = a; c3[n + NNODES] = b; c3[n + 2 * NNODES] = c;
}

// chbo[n,m] = chi[n,m] * s[n]
__global__ void chbo_kernel(const float* __restrict__ chi, const float* __restrict__ s,
                            float* __restrict__ chbo) {
    const int idx = blockIdx.x * 256 + threadIdx.x;
    if (idx >= NNODES * 15) return;
    chbo[idx] = chi[idx] * s[idx / 15];
}

extern "C" void kernel_launch(void* const* d_in, const int* in_sizes, int n_in,
                              void* d_out, int out_size, void* d_ws, size_t ws_size,
                              hipStream_t stream)
{
    const float* x   = (const float*)d_in[0];
    const float* chi = (const float*)d_in[1];
    // d_in[2] = z_one_hot : unused
    const float* W1  = (const float*)d_in[3];
    const float* b1  = (const float*)d_in[4];
    const float* W2  = (const float*)d_in[5];
    const float* W3  = (const float*)d_in[6];
    const float* W4  = (const float*)d_in[7];
    const float* b4  = (const float*)d_in[8];

    char* ws = (char*)d_ws;
    bf16_t* W1b  = (bf16_t*)(ws + 0);
    bf16_t* W2t  = (bf16_t*)(ws + 524288);
    bf16_t* W4t  = (bf16_t*)(ws + 1048576);
    bf16_t* Wct  = (bf16_t*)(ws + 2621440);
    float*  bc   = (float*) (ws + 3145728);
    float*  u    = (float*) (ws + 3147776);
    float*  c3   = (float*) (ws + 3149824);
    float*  sbuf = (float*) (ws + 3444736);
    bf16_t* G2   = (bf16_t*)(ws + 3543040);
    float*  Wctp = (float*) (ws + 3543040);   // overlaps G2 head; dead before G2 written

    float*  xbo  = (float*)d_out;                          // 24576*512 f32
    float*  chbo = (float*)d_out + (size_t)NNODES * 512;   // 24576*15 f32
    bf16_t* Xb   = (bf16_t*)d_out;   // chunk0 head scratch; dead before final GEMM writes xbo

    // prep
    cast8_kernel<<<6144, 256, 0, stream>>>(x, Xb, 1572864);
    prep_kernel<<<4224, 256, 0, stream>>>(W1, W1b, W2, W2t, W4, W4t);
    vecmat_kernel<<<2, 256, 0, stream>>>(b1, W1, u);
    vecmat_kernel<<<2, 256, 0, stream>>>(u, W2, bc);
    c3_kernel<<<96, 256, 0, stream>>>(chi, c3);
    hipMemsetAsync(sbuf, 0, NNODES * sizeof(float), stream);

    // Wct = (W1@W2)^T via split-K partials + reduce
    gemm8_kernel<<<dim3(2, 2, 4), 512, 0, stream>>>(W2t, W1b, Wctp, 512, 128, 512);
    wct_reduce_kernel<<<1024, 256, 0, stream>>>(Wctp, Wct);

    // G-GEMM fused epilogue: G2 = bf16(g^2) ; s += g.W3
    gemm16_kernel<<<dim3(128, 2), 1024, 0, stream>>>(
        Xb, Wct, bc, G2, 512, 512, 3, W3, sbuf);

    // chi_bo = chi * s
    chbo_kernel<<<1440, 256, 0, stream>>>(chi, sbuf, chbo);

    // x_bo = silu( sum_l c_l * (G2 @ W4_l) + b4 )
    gemm16f_kernel<<<dim3(128, 2), 1024, 0, stream>>>(G2, W4t, b4, c3, xbo);
}

// Round 14
// 159.803 us; speedup vs baseline: 1.1007x; 1.1007x over previous
//
#include <hip/hip_runtime.h>

typedef __bf16 bf16_t;
typedef __bf16 bf16x8 __attribute__((ext_vector_type(8)));
typedef __bf16 bf16x4 __attribute__((ext_vector_type(4)));
typedef float f32x4 __attribute__((ext_vector_type(4)));

#define BK 64
#define NNODES 24576

// ws layout (bytes):
//   0        W1b   (512*512 bf16)  = 524288
//   524288   W2t   (512*512 bf16)  = 524288
//   1048576  W4t   (512*1536 bf16) = 1572864
//   2621440  Wct   (512*512 bf16)  = 524288
//   3145728  bc    (512 f32)       = 2048
//   3147776  u     (512 f32)       = 2048
//   3149824  A3    (24576*1536 bf16) = 75497472  [Wctp (4MB f32) overlaps A3
//            head: consumed by wct_reduce BEFORE gemm16x writes A3]
// d_out chunk0 (48MB f32 xbo, dead until final GEMM):
//   25165824 c3    (3*24576 f32)   = 294912
//   25460736 sbuf  (24576 f32)     = 98304
//   (both consumed before the final GEMM overwrites chunk0 with xbo)

__device__ __forceinline__ void g2l16(const void* g, void* l) {
    __builtin_amdgcn_global_load_lds((__attribute__((address_space(1))) void*)(g),
                                     (__attribute__((address_space(3))) void*)(l),
                                     16, 0, 0);
}

#define SB()  __builtin_amdgcn_sched_barrier(0)
#define BAR() __builtin_amdgcn_s_barrier()

// ============ G-GEMM: A = f32 x consumed directly (fused cast) ============
// 16 waves, tile 192x256, BK=64, single barrier per K-tile (R9 hazard model).
// A staging: 3x float4/thread -> cvt bf16 -> ds_write_b64 to the swizzled
// layout contract LDS[(row*128+cb)^((row&7)<<4)] = A[row][cb].
// Epilogue (R11 mode-3): A3[r, l*512+c] = c3[l][r]*g^2 ; sbuf[r] += g.W3.
__global__ __launch_bounds__(1024)
void gemm16x_kernel(const float* __restrict__ X, const bf16_t* __restrict__ Bt,
                    const float* __restrict__ bias, bf16_t* __restrict__ A3,
                    const float* __restrict__ W3, const float* __restrict__ c3v,
                    float* __restrict__ sbuf)
{
    __shared__ __align__(16) bf16_t lA[2][12288];   // 192 rows x 128B per buf
    __shared__ __align__(16) bf16_t lB[2][16384];   // 256 rows x 128B per buf

    const int tid  = threadIdx.x;
    const int lane = tid & 63;
    const int wave = tid >> 6;       // 0..15
    const int wr   = wave >> 2;
    const int wc   = wave & 3;
    const int l15  = lane & 15;
    const int lh   = lane >> 4;

    const int bm = blockIdx.x;
    const int bn = blockIdx.y;

    const size_t strbB = 1024;       // Wct row = 512 bf16

    const int q0 = tid * 16;
    const size_t roB = (size_t)(q0 >> 7) * strbB + ((q0 ^ (((q0 >> 7) & 7) << 4)) & 127);
    const char* gB = (const char*)Bt + (size_t)bn * 256 * strbB + roB;
    char* baseA = (char*)&lA[0][0];
    char* baseB = (char*)&lB[0][0];

    auto stageB = [&](int t, int buf) {
        const size_t kb = (size_t)t * 128;
        g2l16(gB + kb,                baseB + buf * 32768 + q0);
        g2l16(gB + kb + 128 * strbB,  baseB + buf * 32768 + 16384 + q0);
    };

    // A reg-stage addressing: round r covers rows r*64..r*64+63
    const int arow0 = tid >> 4;              // 0..63
    const int e4    = (tid & 15) * 4;        // f32 col 0..60
    const float* gx = X + (size_t)(bm * 192 + arow0) * 512 + e4;
    const int woff0 = ((arow0 * 128) + e4 * 2) ^ ((arow0 & 7) << 4);

    float4 fA[3];
    auto loadA = [&](int t) {
#pragma unroll
        for (int r = 0; r < 3; ++r)
            fA[r] = *(const float4*)(gx + (size_t)r * 64 * 512 + t * 64);
    };
    auto writeA = [&](int buf) {
        char* d = baseA + buf * 24576;
#pragma unroll
        for (int r = 0; r < 3; ++r) {
            bf16x4 o;
            o[0] = (bf16_t)fA[r].x; o[1] = (bf16_t)fA[r].y;
            o[2] = (bf16_t)fA[r].z; o[3] = (bf16_t)fA[r].w;
            *(bf16x4*)(d + r * 8192 + woff0) = o;
        }
    };

    const int swzr = (l15 & 7) << 4;
    const int xk0  = (lh * 16) ^ swzr;
    const int xk1  = (64 + lh * 16) ^ swzr;
    const int aOff = (wr * 48 + l15) * 128;
    const int bOff = (wc * 64 + l15) * 128;

    f32x4 acc[3][4] = {};

    // prologue: tile 0
    loadA(0); stageB(0, 0);
    asm volatile("s_waitcnt vmcnt(2)" ::: "memory");   // A loads (oldest 3 of 5)
    writeA(0);

    for (int t = 0; t < 8; ++t) {
        const int buf = t & 1;

        asm volatile("s_waitcnt vmcnt(0) lgkmcnt(0)" ::: "memory");
        BAR();
        SB();

        if (t < 7) { loadA(t + 1); stageB(t + 1, buf ^ 1); }
        SB();

        bf16x8 af[3][2], bf[4][2];
        {
            const char* _pa = baseA + buf * 24576 + aOff;
#pragma unroll
            for (int m = 0; m < 3; ++m) {
                af[m][0] = *(const bf16x8*)(_pa + m * 2048 + xk0);
                af[m][1] = *(const bf16x8*)(_pa + m * 2048 + xk1);
            }
            const char* _pb = baseB + buf * 32768 + bOff;
#pragma unroll
            for (int n = 0; n < 4; ++n) {
                bf[n][0] = *(const bf16x8*)(_pb + n * 2048 + xk0);
                bf[n][1] = *(const bf16x8*)(_pb + n * 2048 + xk1);
            }
        }

        __builtin_amdgcn_s_setprio(1);
#pragma unroll
        for (int m = 0; m < 3; ++m)
#pragma unroll
        for (int n = 0; n < 4; ++n)
#pragma unroll
        for (int kk = 0; kk < 2; ++kk)
            acc[m][n] = __builtin_amdgcn_mfma_f32_16x16x32_bf16(
                af[m][kk], bf[n][kk], acc[m][n], 0, 0, 0);
        __builtin_amdgcn_s_setprio(0);

        if (t < 7) {
            asm volatile("s_waitcnt vmcnt(2)" ::: "memory");   // retire A loads
            SB();
            writeA(buf ^ 1);
        }
        SB();
    }

    // epilogue: A3 = c_l * g^2 ; sbuf[r] += g.W3
    const int gr0 = bm * 192 + wr * 48 + lh * 4;
    const int gc0 = bn * 256 + wc * 64 + l15;
    float w3v[4], bv[4];
#pragma unroll
    for (int n = 0; n < 4; ++n) {
        w3v[n] = W3[gc0 + n * 16];
        bv[n]  = bias[gc0 + n * 16];
    }
#pragma unroll
    for (int m = 0; m < 3; ++m)
#pragma unroll
    for (int j = 0; j < 4; ++j) {
        const int r = gr0 + m * 16 + j;
        float g[4], p = 0.f;
#pragma unroll
        for (int n = 0; n < 4; ++n) {
            g[n] = acc[m][n][j] + bv[n];
            p += g[n] * w3v[n];
        }
        p += __shfl_xor(p, 1); p += __shfl_xor(p, 2);
        p += __shfl_xor(p, 4); p += __shfl_xor(p, 8);
        if (l15 == 0) atomicAdd(&sbuf[r], p);
        const float c0 = c3v[r], c1 = c3v[r + NNODES], c2 = c3v[r + 2 * NNODES];
        bf16_t* arow = A3 + (size_t)r * 1536 + gc0;
#pragma unroll
        for (int n = 0; n < 4; ++n) {
            const float g2 = g[n] * g[n];
            arow[n * 16]        = (bf16_t)(c0 * g2);
            arow[n * 16 + 512]  = (bf16_t)(c1 * g2);
            arow[n * 16 + 1024] = (bf16_t)(c2 * g2);
        }
    }
}

// ============ 16-wave GEMM (bf16 A) — final GEMM (mode 1) ============
__global__ __launch_bounds__(1024)
void gemm16_kernel(const bf16_t* __restrict__ A, const bf16_t* __restrict__ Bt,
                   const float* __restrict__ bias, void* __restrict__ Cout,
                   int N, int K, int mode)
{
    __shared__ __align__(16) bf16_t lA[2][12288];
    __shared__ __align__(16) bf16_t lB[2][16384];

    const int tid  = threadIdx.x;
    const int lane = tid & 63;
    const int wave = tid >> 6;
    const int wr   = wave >> 2;
    const int wc   = wave & 3;
    const int l15  = lane & 15;
    const int lh   = lane >> 4;

    const int bm = blockIdx.x;
    const int bn = blockIdx.y;

    const size_t strb = (size_t)K * 2;

    const int q0 = tid * 16;
    const size_t ro = (size_t)(q0 >> 7) * strb + ((q0 ^ (((q0 >> 7) & 7) << 4)) & 127);
    const char* gA = (const char*)A  + (size_t)bm * 192 * strb + ro;
    const char* gB = (const char*)Bt + (size_t)bn * 256 * strb + ro;
    char* baseA = (char*)&lA[0][0];
    char* baseB = (char*)&lB[0][0];

    auto stage = [&](int t, int buf) {
        const size_t kb = (size_t)t * 128;
        g2l16(gA + kb, baseA + buf * 24576 + q0);
        if (tid < 512)
            g2l16(gA + kb + 128 * strb, baseA + buf * 24576 + 16384 + q0);
        g2l16(gB + kb, baseB + buf * 32768 + q0);
        g2l16(gB + kb + 128 * strb, baseB + buf * 32768 + 16384 + q0);
    };

    const int swzr = (l15 & 7) << 4;
    const int xk0  = (lh * 16) ^ swzr;
    const int xk1  = (64 + lh * 16) ^ swzr;
    const int aOff = (wr * 48 + l15) * 128;
    const int bOff = (wc * 64 + l15) * 128;

    f32x4 acc[3][4] = {};

    const int T = K / BK;
    stage(0, 0);

    for (int t = 0; t < T; ++t) {
        const int buf = t & 1;

        asm volatile("s_waitcnt vmcnt(0)" ::: "memory");
        BAR();
        SB();

        if (t + 1 < T) stage(t + 1, buf ^ 1);
        SB();

        bf16x8 af[3][2], bf[4][2];
        {
            const char* _pa = baseA + buf * 24576 + aOff;
#pragma unroll
            for (int m = 0; m < 3; ++m) {
                af[m][0] = *(const bf16x8*)(_pa + m * 2048 + xk0);
                af[m][1] = *(const bf16x8*)(_pa + m * 2048 + xk1);
            }
            const char* _pb = baseB + buf * 32768 + bOff;
#pragma unroll
            for (int n = 0; n < 4; ++n) {
                bf[n][0] = *(const bf16x8*)(_pb + n * 2048 + xk0);
                bf[n][1] = *(const bf16x8*)(_pb + n * 2048 + xk1);
            }
        }

        __builtin_amdgcn_s_setprio(1);
#pragma unroll
        for (int m = 0; m < 3; ++m)
#pragma unroll
        for (int n = 0; n < 4; ++n)
#pragma unroll
        for (int kk = 0; kk < 2; ++kk)
            acc[m][n] = __builtin_amdgcn_mfma_f32_16x16x32_bf16(
                af[m][kk], bf[n][kk], acc[m][n], 0, 0, 0);
        __builtin_amdgcn_s_setprio(0);
    }

    const int gr0 = bm * 192 + wr * 48 + lh * 4;
    const int gc0 = bn * 256 + wc * 64 + l15;
    if (mode == 0) {
        bf16_t* C = (bf16_t*)Cout;
#pragma unroll
        for (int m = 0; m < 3; ++m)
#pragma unroll
        for (int n = 0; n < 4; ++n) {
            const int c = gc0 + n * 16;
            const float bv = bias ? bias[c] : 0.f;
#pragma unroll
            for (int j = 0; j < 4; ++j)
                C[(size_t)(gr0 + m * 16 + j) * N + c] = (bf16_t)(acc[m][n][j] + bv);
        }
    } else {
        float* C = (float*)Cout;
#pragma unroll
        for (int m = 0; m < 3; ++m)
#pragma unroll
        for (int n = 0; n < 4; ++n) {
            const int c = gc0 + n * 16;
            const float bv = bias[c];
#pragma unroll
            for (int j = 0; j < 4; ++j) {
                float v = acc[m][n][j] + bv;
                C[(size_t)(gr0 + m * 16 + j) * N + c] = v / (1.f + __expf(-v));
            }
        }
    }
}

// ============ 8-wave GEMM (split-K) — Wct partials only ============
__global__ __launch_bounds__(512)
void gemm8_kernel(const bf16_t* __restrict__ A, const bf16_t* __restrict__ Bt,
                  void* __restrict__ Cout, int N, int K, int LD)
{
    __shared__ __align__(16) bf16_t lA[2][16384];
    __shared__ __align__(16) bf16_t lB[2][16384];

    const int tid  = threadIdx.x;
    const int lane = tid & 63;
    const int wave = tid >> 6;
    const int wr   = wave >> 2;
    const int wc   = wave & 3;
    const int l15  = lane & 15;
    const int lh   = lane >> 4;

    const int bm = blockIdx.x;
    const int bn = blockIdx.y;
    const int bz = blockIdx.z;

    const size_t strb = (size_t)LD * 2;
    const size_t zoff = (size_t)bz * K * 2;

    const int q0 = tid * 16;
    const size_t rowOff = (size_t)(q0 >> 7) * strb + ((q0 ^ (((q0 >> 7) & 7) << 4)) & 127);
    const char* gA = (const char*)A  + (size_t)bm * 256 * strb + zoff + rowOff;
    const char* gB = (const char*)Bt + (size_t)bn * 256 * strb + zoff + rowOff;
    char* baseA = (char*)&lA[0][0];
    char* baseB = (char*)&lB[0][0];

    auto stageA = [&](int t, int buf, int r) {
        g2l16(gA + (size_t)t * 128 + (size_t)(r * 64) * strb,
              baseA + buf * 32768 + r * 8192 + q0);
    };
    auto stageB = [&](int t, int buf, int r) {
        g2l16(gB + (size_t)t * 128 + (size_t)(r * 64) * strb,
              baseB + buf * 32768 + r * 8192 + q0);
    };

    const int swzr = (l15 & 7) << 4;
    const int xk0  = (lh * 16) ^ swzr;
    const int xk1  = (64 + lh * 16) ^ swzr;
    const int aOff = wr * 16384 + l15 * 128;
    const int bOff = wc * 8192 + l15 * 128;

    f32x4 acc[2][2][4][2] = {};

    const int T = K / BK;

#pragma unroll
    for (int r = 0; r < 4; ++r) { stageA(0, 0, r); stageB(0, 0, r); }

    for (int t = 0; t < T; ++t) {
        const int buf = t & 1, nbuf = buf ^ 1;

        asm volatile("s_waitcnt vmcnt(0)" ::: "memory");
        BAR();
        SB();

        if (t + 1 < T) {
#pragma unroll
            for (int r = 0; r < 4; ++r) { stageA(t + 1, nbuf, r); stageB(t + 1, nbuf, r); }
        }
        SB();

        bf16x8 af[8][2], bf[4][2];
        {
            const char* _pa = baseA + buf * 32768 + aOff;
#pragma unroll
            for (int i = 0; i < 8; ++i) {
                af[i][0] = *(const bf16x8*)(_pa + i * 2048 + xk0);
                af[i][1] = *(const bf16x8*)(_pa + i * 2048 + xk1);
            }
            const char* _pb = baseB + buf * 32768 + bOff;
#pragma unroll
            for (int j = 0; j < 4; ++j) {
                bf[j][0] = *(const bf16x8*)(_pb + j * 2048 + xk0);
                bf[j][1] = *(const bf16x8*)(_pb + j * 2048 + xk1);
            }
        }

        __builtin_amdgcn_s_setprio(1);
#pragma unroll
        for (int mh = 0; mh < 2; ++mh)
#pragma unroll
        for (int nh = 0; nh < 2; ++nh)
#pragma unroll
        for (int m = 0; m < 4; ++m)
#pragma unroll
        for (int n = 0; n < 2; ++n)
#pragma unroll
        for (int kk = 0; kk < 2; ++kk)
            acc[mh][nh][m][n] = __builtin_amdgcn_mfma_f32_16x16x32_bf16(
                af[mh * 4 + m][kk], bf[nh * 2 + n][kk], acc[mh][nh][m][n], 0, 0, 0);
        __builtin_amdgcn_s_setprio(0);
    }

    float* C = (float*)Cout + (size_t)bz * 512 * 512;
    const int gr0 = bm * 256 + wr * 128 + lh * 4;
    const int gc0 = bn * 256 + wc * 64 + l15;
#pragma unroll
    for (int mh = 0; mh < 2; ++mh)
#pragma unroll
    for (int nh = 0; nh < 2; ++nh)
#pragma unroll
    for (int m = 0; m < 4; ++m)
#pragma unroll
    for (int n = 0; n < 2; ++n) {
        const int c = gc0 + nh * 32 + n * 16;
#pragma unroll
        for (int j = 0; j < 4; ++j)
            C[(size_t)(gr0 + (mh * 4 + m) * 16 + j) * N + c] = acc[mh][nh][m][n][j];
    }
}

__global__ void wct_reduce_kernel(const float* __restrict__ p, bf16_t* __restrict__ out) {
    const int i = blockIdx.x * 256 + threadIdx.x;   // < 262144
    out[i] = (bf16_t)(p[i] + p[i + 262144] + p[i + 524288] + p[i + 786432]);
}

// fused weight prep: [0,128) cast W1; [128,1152) transpose W2; [1152,4224) transpose W4
__global__ void prep_kernel(const float* __restrict__ W1, bf16_t* __restrict__ W1b,
                            const float* __restrict__ W2, bf16_t* __restrict__ W2t,
                            const float* __restrict__ W4, bf16_t* __restrict__ W4t)
{
    const int b = blockIdx.x;
    if (b < 128) {
        const int i = b * 256 + threadIdx.x;
        const float4* p = (const float4*)W1 + (size_t)i * 2;
        float4 a = p[0], c = p[1];
        bf16x8 v;
        v[0] = (bf16_t)a.x; v[1] = (bf16_t)a.y; v[2] = (bf16_t)a.z; v[3] = (bf16_t)a.w;
        v[4] = (bf16_t)c.x; v[5] = (bf16_t)c.y; v[6] = (bf16_t)c.z; v[7] = (bf16_t)c.w;
        *(bf16x8*)(W1b + (size_t)i * 8) = v;
    } else if (b < 1152) {
        const int idx = (b - 128) * 256 + threadIdx.x;
        const int c = idx >> 9, r = idx & 511;
        W2t[idx] = (bf16_t)W2[(size_t)r * 512 + c];
    } else {
        const int idx = (b - 1152) * 256 + threadIdx.x;
        const int c = idx / 1536, r = idx - c * 1536;
        W4t[idx] = (bf16_t)W4[(size_t)r * 512 + c];
    }
}

// u[t] = sum_i v[i] * W[i][t]
__global__ void vecmat_kernel(const float* __restrict__ v, const float* __restrict__ W,
                              float* __restrict__ out) {
    const int t = blockIdx.x * blockDim.x + threadIdx.x;
    if (t >= 512) return;
    float s = 0.f;
    for (int i = 0; i < 512; ++i) s += v[i] * W[i * 512 + t];
    out[t] = s;
}

// c3[l][n] = sum_{m in seg l} chi[n,m]^2 ; also zeroes sbuf (replay-safe)
__global__ void c3_kernel(const float* __restrict__ chi, float* __restrict__ c3,
                          float* __restrict__ sbuf) {
    const int n = blockIdx.x * 256 + threadIdx.x;
    if (n >= NNODES) return;
    const float* ch = chi + (size_t)n * 15;
    float a = 0.f, b = 0.f, c = 0.f;
#pragma unroll
    for (int m = 0; m < 3; ++m)  a += ch[m] * ch[m];
#pragma unroll
    for (int m = 3; m < 8; ++m)  b += ch[m] * ch[m];
#pragma unroll
    for (int m = 8; m < 15; ++m) c += ch[m] * ch[m];
    c3[n] = a; c3[n + NNODES] = b; c3[n + 2 * NNODES] = c;
    sbuf[n] = 0.f;
}

// chbo[n,m] = chi[n,m] * s[n]
__global__ void chbo_kernel(const float* __restrict__ chi, const float* __restrict__ s,
                            float* __restrict__ chbo) {
    const int idx = blockIdx.x * 256 + threadIdx.x;
    if (idx >= NNODES * 15) return;
    chbo[idx] = chi[idx] * s[idx / 15];
}

extern "C" void kernel_launch(void* const* d_in, const int* in_sizes, int n_in,
                              void* d_out, int out_size, void* d_ws, size_t ws_size,
                              hipStream_t stream)
{
    const float* x   = (const float*)d_in[0];
    const float* chi = (const float*)d_in[1];
    // d_in[2] = z_one_hot : unused
    const float* W1  = (const float*)d_in[3];
    const float* b1  = (const float*)d_in[4];
    const float* W2  = (const float*)d_in[5];
    const float* W3  = (const float*)d_in[6];
    const float* W4  = (const float*)d_in[7];
    const float* b4  = (const float*)d_in[8];

    char* ws = (char*)d_ws;
    bf16_t* W1b  = (bf16_t*)(ws + 0);
    bf16_t* W2t  = (bf16_t*)(ws + 524288);
    bf16_t* W4t  = (bf16_t*)(ws + 1048576);
    bf16_t* Wct  = (bf16_t*)(ws + 2621440);
    float*  bc   = (float*) (ws + 3145728);
    float*  u    = (float*) (ws + 3147776);
    bf16_t* A3   = (bf16_t*)(ws + 3149824);
    float*  Wctp = (float*) (ws + 3149824);   // overlaps A3 head; dead before A3 written

    float*  xbo  = (float*)d_out;                          // 24576*512 f32
    float*  chbo = (float*)d_out + (size_t)NNODES * 512;   // 24576*15 f32
    // dead chunk0 region as scratch (consumed before final GEMM writes xbo):
    char*   c0s  = (char*)d_out;
    float*  c3   = (float*) (c0s + 25165824);
    float*  sbuf = (float*) (c0s + 25460736);

    // prep
    prep_kernel<<<4224, 256, 0, stream>>>(W1, W1b, W2, W2t, W4, W4t);
    vecmat_kernel<<<2, 256, 0, stream>>>(b1, W1, u);
    vecmat_kernel<<<2, 256, 0, stream>>>(u, W2, bc);
    c3_kernel<<<96, 256, 0, stream>>>(chi, c3, sbuf);

    // Wct = (W1@W2)^T via split-K partials + reduce
    gemm8_kernel<<<dim3(2, 2, 4), 512, 0, stream>>>(W2t, W1b, Wctp, 512, 128, 512);
    wct_reduce_kernel<<<1024, 256, 0, stream>>>(Wctp, Wct);

    // G-GEMM (consumes f32 x directly): A3 = c_l * g^2 ; sbuf += g.W3
    gemm16x_kernel<<<dim3(128, 2), 1024, 0, stream>>>(x, Wct, bc, A3, W3, c3, sbuf);

    // chi_bo = chi * s
    chbo_kernel<<<1440, 256, 0, stream>>>(chi, sbuf, chbo);

    // x_bo = silu(A3 @ W4 + b4)
    gemm16_kernel<<<dim3(128, 2), 1024, 0, stream>>>(A3, W4t, b4, xbo, 512, 1536, 1);
}

// Round 15
// 155.347 us; speedup vs baseline: 1.1323x; 1.0287x over previous
//
#include <hip/hip_runtime.h>

typedef __bf16 bf16_t;
typedef __bf16 bf16x8 __attribute__((ext_vector_type(8)));
typedef __bf16 bf16x4 __attribute__((ext_vector_type(4)));
typedef float f32x4 __attribute__((ext_vector_type(4)));

#define BK 64
#define NNODES 24576

// ws layout (bytes):
//   0        W1b   (512*512 bf16)  = 524288
//   524288   W2t   (512*512 bf16)  = 524288
//   1048576  W4t   (512*1536 bf16) = 1572864
//   2621440  Wct   (512*512 bf16)  = 524288
//   3145728  bc    (512 f32)       = 2048
//   3147776  u     (512 f32)       = 2048
//   3149824  A3    (24576*1536 bf16) = 75497472  [Wctp (4MB f32) overlaps A3
//            head: consumed by wct_reduce BEFORE gemm16x writes A3]
// d_out chunk0 (48MB f32 xbo, dead until final GEMM):
//   25165824 c3    (3*24576 f32)   = 294912
//   25460736 sbuf  (24576 f32)     = 98304

__device__ __forceinline__ void g2l16(const void* g, void* l) {
    __builtin_amdgcn_global_load_lds((__attribute__((address_space(1))) void*)(g),
                                     (__attribute__((address_space(3))) void*)(l),
                                     16, 0, 0);
}

#define SB()  __builtin_amdgcn_sched_barrier(0)
#define BAR() __builtin_amdgcn_s_barrier()

// ============ G-GEMM: A = f32 x consumed directly (fused cast) ============
// 16 waves, tile 192x256, BK=64, single barrier per K-tile.
// Epilogue: sbuf[r] += g.W3 (atomic); A3[r, l*512+c] = c3[l][r]*g^2 written
// via LDS round-trip -> fully coalesced 16B/lane stores (fixes the 32B-granule
// scatter that cost ~45us in R11/R13).
__global__ __launch_bounds__(1024)
void gemm16x_kernel(const float* __restrict__ X, const bf16_t* __restrict__ Bt,
                    const float* __restrict__ bias, bf16_t* __restrict__ A3,
                    const float* __restrict__ W3, const float* __restrict__ c3v,
                    float* __restrict__ sbuf)
{
    __shared__ __align__(16) char smem[114688];
    char* baseA = smem;            // 2 x 24576 (192 rows x 128B per buf)
    char* baseB = smem + 49152;    // 2 x 32768 (256 rows x 128B per buf)

    const int tid  = threadIdx.x;
    const int lane = tid & 63;
    const int wave = tid >> 6;       // 0..15
    const int wr   = wave >> 2;
    const int wc   = wave & 3;
    const int l15  = lane & 15;
    const int lh   = lane >> 4;

    const int bm = blockIdx.x;
    const int bn = blockIdx.y;

    const size_t strbB = 1024;       // Wct row = 512 bf16

    const int q0 = tid * 16;
    const size_t roB = (size_t)(q0 >> 7) * strbB + ((q0 ^ (((q0 >> 7) & 7) << 4)) & 127);
    const char* gB = (const char*)Bt + (size_t)bn * 256 * strbB + roB;

    auto stageB = [&](int t, int buf) {
        const size_t kb = (size_t)t * 128;
        g2l16(gB + kb,                baseB + buf * 32768 + q0);
        g2l16(gB + kb + 128 * strbB,  baseB + buf * 32768 + 16384 + q0);
    };

    // A reg-stage: round r covers rows r*64..r*64+63
    const int arow0 = tid >> 4;              // 0..63
    const int e4    = (tid & 15) * 4;        // f32 col 0..60
    const float* gx = X + (size_t)(bm * 192 + arow0) * 512 + e4;
    const int woff0 = ((arow0 * 128) + e4 * 2) ^ ((arow0 & 7) << 4);

    float4 fA[3];
    auto loadA = [&](int t) {
#pragma unroll
        for (int r = 0; r < 3; ++r)
            fA[r] = *(const float4*)(gx + (size_t)r * 64 * 512 + t * 64);
    };
    auto writeA = [&](int buf) {
        char* d = baseA + buf * 24576;
#pragma unroll
        for (int r = 0; r < 3; ++r) {
            bf16x4 o;
            o[0] = (bf16_t)fA[r].x; o[1] = (bf16_t)fA[r].y;
            o[2] = (bf16_t)fA[r].z; o[3] = (bf16_t)fA[r].w;
            *(bf16x4*)(d + r * 8192 + woff0) = o;
        }
    };

    const int swzr = (l15 & 7) << 4;
    const int xk0  = (lh * 16) ^ swzr;
    const int xk1  = (64 + lh * 16) ^ swzr;
    const int aOff = (wr * 48 + l15) * 128;
    const int bOff = (wc * 64 + l15) * 128;

    f32x4 acc[3][4] = {};

    loadA(0); stageB(0, 0);
    asm volatile("s_waitcnt vmcnt(2)" ::: "memory");
    writeA(0);

    for (int t = 0; t < 8; ++t) {
        const int buf = t & 1;

        asm volatile("s_waitcnt vmcnt(0) lgkmcnt(0)" ::: "memory");
        BAR();
        SB();

        if (t < 7) { loadA(t + 1); stageB(t + 1, buf ^ 1); }
        SB();

        bf16x8 af[3][2], bf[4][2];
        {
            const char* _pa = baseA + buf * 24576 + aOff;
#pragma unroll
            for (int m = 0; m < 3; ++m) {
                af[m][0] = *(const bf16x8*)(_pa + m * 2048 + xk0);
                af[m][1] = *(const bf16x8*)(_pa + m * 2048 + xk1);
            }
            const char* _pb = baseB + buf * 32768 + bOff;
#pragma unroll
            for (int n = 0; n < 4; ++n) {
                bf[n][0] = *(const bf16x8*)(_pb + n * 2048 + xk0);
                bf[n][1] = *(const bf16x8*)(_pb + n * 2048 + xk1);
            }
        }

        __builtin_amdgcn_s_setprio(1);
#pragma unroll
        for (int m = 0; m < 3; ++m)
#pragma unroll
        for (int n = 0; n < 4; ++n)
#pragma unroll
        for (int kk = 0; kk < 2; ++kk)
            acc[m][n] = __builtin_amdgcn_mfma_f32_16x16x32_bf16(
                af[m][kk], bf[n][kk], acc[m][n], 0, 0, 0);
        __builtin_amdgcn_s_setprio(0);

        if (t < 7) {
            asm volatile("s_waitcnt vmcnt(2)" ::: "memory");
            SB();
            writeA(buf ^ 1);
        }
        SB();
    }

    // ---- epilogue ----
    BAR();   // all waves done with LDS before reuse
    // stage g^2 into pitched LDS tile [192][264] bf16 (pitch 528B, 16B-aligned)
    bf16_t* sg = (bf16_t*)smem;
    const int gr0 = bm * 192 + wr * 48 + lh * 4;
    const int gc0 = bn * 256 + wc * 64 + l15;
    const int lr0 = wr * 48 + lh * 4;
    const int lc0 = wc * 64 + l15;
    float w3v[4], bv[4];
#pragma unroll
    for (int n = 0; n < 4; ++n) {
        w3v[n] = W3[gc0 + n * 16];
        bv[n]  = bias[gc0 + n * 16];
    }
#pragma unroll
    for (int m = 0; m < 3; ++m)
#pragma unroll
    for (int j = 0; j < 4; ++j) {
        const int r = gr0 + m * 16 + j;
        float g[4], p = 0.f;
#pragma unroll
        for (int n = 0; n < 4; ++n) {
            g[n] = acc[m][n][j] + bv[n];
            p += g[n] * w3v[n];
        }
        p += __shfl_xor(p, 1); p += __shfl_xor(p, 2);
        p += __shfl_xor(p, 4); p += __shfl_xor(p, 8);
        if (l15 == 0) atomicAdd(&sbuf[r], p);
        bf16_t* srow = sg + (lr0 + m * 16 + j) * 264 + lc0;
#pragma unroll
        for (int n = 0; n < 4; ++n)
            srow[n * 16] = (bf16_t)(g[n] * g[n]);
    }
    BAR();
    // coalesced write-out: 6 passes x 32 rows; 32 threads x bf16x8 per row
    const int rl = tid >> 5;             // 0..31
    const int cb = (tid & 31) * 8;       // elem col 0..248
#pragma unroll
    for (int pass = 0; pass < 6; ++pass) {
        const int row = pass * 32 + rl;
        const bf16x8 v = *(const bf16x8*)((const char*)sg + row * 528 + cb * 2);
        float f[8];
#pragma unroll
        for (int j = 0; j < 8; ++j) f[j] = (float)v[j];
        const int grow = bm * 192 + row;
#pragma unroll
        for (int l = 0; l < 3; ++l) {
            const float c = c3v[grow + l * NNODES];
            bf16x8 o;
#pragma unroll
            for (int j = 0; j < 8; ++j) o[j] = (bf16_t)(c * f[j]);
            *(bf16x8*)(A3 + (size_t)grow * 1536 + l * 512 + bn * 256 + cb) = o;
        }
    }
}

// ============ 16-wave GEMM (bf16 A) — final GEMM ============
__global__ __launch_bounds__(1024)
void gemm16_kernel(const bf16_t* __restrict__ A, const bf16_t* __restrict__ Bt,
                   const float* __restrict__ bias, void* __restrict__ Cout,
                   int N, int K, int mode)
{
    __shared__ __align__(16) bf16_t lA[2][12288];
    __shared__ __align__(16) bf16_t lB[2][16384];

    const int tid  = threadIdx.x;
    const int lane = tid & 63;
    const int wave = tid >> 6;
    const int wr   = wave >> 2;
    const int wc   = wave & 3;
    const int l15  = lane & 15;
    const int lh   = lane >> 4;

    const int bm = blockIdx.x;
    const int bn = blockIdx.y;

    const size_t strb = (size_t)K * 2;

    const int q0 = tid * 16;
    const size_t ro = (size_t)(q0 >> 7) * strb + ((q0 ^ (((q0 >> 7) & 7) << 4)) & 127);
    const char* gA = (const char*)A  + (size_t)bm * 192 * strb + ro;
    const char* gB = (const char*)Bt + (size_t)bn * 256 * strb + ro;
    char* baseA = (char*)&lA[0][0];
    char* baseB = (char*)&lB[0][0];

    auto stage = [&](int t, int buf) {
        const size_t kb = (size_t)t * 128;
        g2l16(gA + kb, baseA + buf * 24576 + q0);
        if (tid < 512)
            g2l16(gA + kb + 128 * strb, baseA + buf * 24576 + 16384 + q0);
        g2l16(gB + kb, baseB + buf * 32768 + q0);
        g2l16(gB + kb + 128 * strb, baseB + buf * 32768 + 16384 + q0);
    };

    const int swzr = (l15 & 7) << 4;
    const int xk0  = (lh * 16) ^ swzr;
    const int xk1  = (64 + lh * 16) ^ swzr;
    const int aOff = (wr * 48 + l15) * 128;
    const int bOff = (wc * 64 + l15) * 128;

    f32x4 acc[3][4] = {};

    const int T = K / BK;
    stage(0, 0);

    for (int t = 0; t < T; ++t) {
        const int buf = t & 1;

        asm volatile("s_waitcnt vmcnt(0)" ::: "memory");
        BAR();
        SB();

        if (t + 1 < T) stage(t + 1, buf ^ 1);
        SB();

        bf16x8 af[3][2], bf[4][2];
        {
            const char* _pa = baseA + buf * 24576 + aOff;
#pragma unroll
            for (int m = 0; m < 3; ++m) {
                af[m][0] = *(const bf16x8*)(_pa + m * 2048 + xk0);
                af[m][1] = *(const bf16x8*)(_pa + m * 2048 + xk1);
            }
            const char* _pb = baseB + buf * 32768 + bOff;
#pragma unroll
            for (int n = 0; n < 4; ++n) {
                bf[n][0] = *(const bf16x8*)(_pb + n * 2048 + xk0);
                bf[n][1] = *(const bf16x8*)(_pb + n * 2048 + xk1);
            }
        }

        __builtin_amdgcn_s_setprio(1);
#pragma unroll
        for (int m = 0; m < 3; ++m)
#pragma unroll
        for (int n = 0; n < 4; ++n)
#pragma unroll
        for (int kk = 0; kk < 2; ++kk)
            acc[m][n] = __builtin_amdgcn_mfma_f32_16x16x32_bf16(
                af[m][kk], bf[n][kk], acc[m][n], 0, 0, 0);
        __builtin_amdgcn_s_setprio(0);
    }

    const int gr0 = bm * 192 + wr * 48 + lh * 4;
    const int gc0 = bn * 256 + wc * 64 + l15;
    if (mode == 0) {
        bf16_t* C = (bf16_t*)Cout;
#pragma unroll
        for (int m = 0; m < 3; ++m)
#pragma unroll
        for (int n = 0; n < 4; ++n) {
            const int c = gc0 + n * 16;
            const float bv = bias ? bias[c] : 0.f;
#pragma unroll
            for (int j = 0; j < 4; ++j)
                C[(size_t)(gr0 + m * 16 + j) * N + c] = (bf16_t)(acc[m][n][j] + bv);
        }
    } else {
        float* C = (float*)Cout;
#pragma unroll
        for (int m = 0; m < 3; ++m)
#pragma unroll
        for (int n = 0; n < 4; ++n) {
            const int c = gc0 + n * 16;
            const float bv = bias[c];
#pragma unroll
            for (int j = 0; j < 4; ++j) {
                float v = acc[m][n][j] + bv;
                C[(size_t)(gr0 + m * 16 + j) * N + c] = v / (1.f + __expf(-v));
            }
        }
    }
}

// ============ 8-wave GEMM (split-K) — Wct partials only ============
__global__ __launch_bounds__(512)
void gemm8_kernel(const bf16_t* __restrict__ A, const bf16_t* __restrict__ Bt,
                  void* __restrict__ Cout, int N, int K, int LD)
{
    __shared__ __align__(16) bf16_t lA[2][16384];
    __shared__ __align__(16) bf16_t lB[2][16384];

    const int tid  = threadIdx.x;
    const int lane = tid & 63;
    const int wave = tid >> 6;
    const int wr   = wave >> 2;
    const int wc   = wave & 3;
    const int l15  = lane & 15;
    const int lh   = lane >> 4;

    const int bm = blockIdx.x;
    const int bn = blockIdx.y;
    const int bz = blockIdx.z;

    const size_t strb = (size_t)LD * 2;
    const size_t zoff = (size_t)bz * K * 2;

    const int q0 = tid * 16;
    const size_t rowOff = (size_t)(q0 >> 7) * strb + ((q0 ^ (((q0 >> 7) & 7) << 4)) & 127);
    const char* gA = (const char*)A  + (size_t)bm * 256 * strb + zoff + rowOff;
    const char* gB = (const char*)Bt + (size_t)bn * 256 * strb + zoff + rowOff;
    char* baseA = (char*)&lA[0][0];
    char* baseB = (char*)&lB[0][0];

    auto stageA = [&](int t, int buf, int r) {
        g2l16(gA + (size_t)t * 128 + (size_t)(r * 64) * strb,
              baseA + buf * 32768 + r * 8192 + q0);
    };
    auto stageB = [&](int t, int buf, int r) {
        g2l16(gB + (size_t)t * 128 + (size_t)(r * 64) * strb,
              baseB + buf * 32768 + r * 8192 + q0);
    };

    const int swzr = (l15 & 7) << 4;
    const int xk0  = (lh * 16) ^ swzr;
    const int xk1  = (64 + lh * 16) ^ swzr;
    const int aOff = wr * 16384 + l15 * 128;
    const int bOff = wc * 8192 + l15 * 128;

    f32x4 acc[2][2][4][2] = {};

    const int T = K / BK;

#pragma unroll
    for (int r = 0; r < 4; ++r) { stageA(0, 0, r); stageB(0, 0, r); }

    for (int t = 0; t < T; ++t) {
        const int buf = t & 1, nbuf = buf ^ 1;

        asm volatile("s_waitcnt vmcnt(0)" ::: "memory");
        BAR();
        SB();

        if (t + 1 < T) {
#pragma unroll
            for (int r = 0; r < 4; ++r) { stageA(t + 1, nbuf, r); stageB(t + 1, nbuf, r); }
        }
        SB();

        bf16x8 af[8][2], bf[4][2];
        {
            const char* _pa = baseA + buf * 32768 + aOff;
#pragma unroll
            for (int i = 0; i < 8; ++i) {
                af[i][0] = *(const bf16x8*)(_pa + i * 2048 + xk0);
                af[i][1] = *(const bf16x8*)(_pa + i * 2048 + xk1);
            }
            const char* _pb = baseB + buf * 32768 + bOff;
#pragma unroll
            for (int j = 0; j < 4; ++j) {
                bf[j][0] = *(const bf16x8*)(_pb + j * 2048 + xk0);
                bf[j][1] = *(const bf16x8*)(_pb + j * 2048 + xk1);
            }
        }

        __builtin_amdgcn_s_setprio(1);
#pragma unroll
        for (int mh = 0; mh < 2; ++mh)
#pragma unroll
        for (int nh = 0; nh < 2; ++nh)
#pragma unroll
        for (int m = 0; m < 4; ++m)
#pragma unroll
        for (int n = 0; n < 2; ++n)
#pragma unroll
        for (int kk = 0; kk < 2; ++kk)
            acc[mh][nh][m][n] = __builtin_amdgcn_mfma_f32_16x16x32_bf16(
                af[mh * 4 + m][kk], bf[nh * 2 + n][kk], acc[mh][nh][m][n], 0, 0, 0);
        __builtin_amdgcn_s_setprio(0);
    }

    float* C = (float*)Cout + (size_t)bz * 512 * 512;
    const int gr0 = bm * 256 + wr * 128 + lh * 4;
    const int gc0 = bn * 256 + wc * 64 + l15;
#pragma unroll
    for (int mh = 0; mh < 2; ++mh)
#pragma unroll
    for (int nh = 0; nh < 2; ++nh)
#pragma unroll
    for (int m = 0; m < 4; ++m)
#pragma unroll
    for (int n = 0; n < 2; ++n) {
        const int c = gc0 + nh * 32 + n * 16;
#pragma unroll
        for (int j = 0; j < 4; ++j)
            C[(size_t)(gr0 + (mh * 4 + m) * 16 + j) * N + c] = acc[mh][nh][m][n][j];
    }
}

__global__ void wct_reduce_kernel(const float* __restrict__ p, bf16_t* __restrict__ out) {
    const int i = blockIdx.x * 256 + threadIdx.x;   // < 262144
    out[i] = (bf16_t)(p[i] + p[i + 262144] + p[i + 524288] + p[i + 786432]);
}

// fused weight prep: [0,128) cast W1; [128,1152) transpose W2; [1152,4224) transpose W4
__global__ void prep_kernel(const float* __restrict__ W1, bf16_t* __restrict__ W1b,
                            const float* __restrict__ W2, bf16_t* __restrict__ W2t,
                            const float* __restrict__ W4, bf16_t* __restrict__ W4t)
{
    const int b = blockIdx.x;
    if (b < 128) {
        const int i = b * 256 + threadIdx.x;
        const float4* p = (const float4*)W1 + (size_t)i * 2;
        float4 a = p[0], c = p[1];
        bf16x8 v;
        v[0] = (bf16_t)a.x; v[1] = (bf16_t)a.y; v[2] = (bf16_t)a.z; v[3] = (bf16_t)a.w;
        v[4] = (bf16_t)c.x; v[5] = (bf16_t)c.y; v[6] = (bf16_t)c.z; v[7] = (bf16_t)c.w;
        *(bf16x8*)(W1b + (size_t)i * 8) = v;
    } else if (b < 1152) {
        const int idx = (b - 128) * 256 + threadIdx.x;
        const int c = idx >> 9, r = idx & 511;
        W2t[idx] = (bf16_t)W2[(size_t)r * 512 + c];
    } else {
        const int idx = (b - 1152) * 256 + threadIdx.x;
        const int c = idx / 1536, r = idx - c * 1536;
        W4t[idx] = (bf16_t)W4[(size_t)r * 512 + c];
    }
}

// u[t] = sum_i v[i] * W[i][t]
__global__ void vecmat_kernel(const float* __restrict__ v, const float* __restrict__ W,
                              float* __restrict__ out) {
    const int t = blockIdx.x * blockDim.x + threadIdx.x;
    if (t >= 512) return;
    float s = 0.f;
    for (int i = 0; i < 512; ++i) s += v[i] * W[i * 512 + t];
    out[t] = s;
}

// c3[l][n] = sum_{m in seg l} chi[n,m]^2 ; also zeroes sbuf (replay-safe)
__global__ void c3_kernel(const float* __restrict__ chi, float* __restrict__ c3,
                          float* __restrict__ sbuf) {
    const int n = blockIdx.x * 256 + threadIdx.x;
    if (n >= NNODES) return;
    const float* ch = chi + (size_t)n * 15;
    float a = 0.f, b = 0.f, c = 0.f;
#pragma unroll
    for (int m = 0; m < 3; ++m)  a += ch[m] * ch[m];
#pragma unroll
    for (int m = 3; m < 8; ++m)  b += ch[m] * ch[m];
#pragma unroll
    for (int m = 8; m < 15; ++m) c += ch[m] * ch[m];
    c3[n] = a; c3[n + NNODES] = b; c3[n + 2 * NNODES] = c;
    sbuf[n] = 0.f;
}

// chbo[n,m] = chi[n,m] * s[n]
__global__ void chbo_kernel(const float* __restrict__ chi, const float* __restrict__ s,
                            float* __restrict__ chbo) {
    const int idx = blockIdx.x * 256 + threadIdx.x;
    if (idx >= NNODES * 15) return;
    chbo[idx] = chi[idx] * s[idx / 15];
}

extern "C" void kernel_launch(void* const* d_in, const int* in_sizes, int n_in,
                              void* d_out, int out_size, void* d_ws, size_t ws_size,
                              hipStream_t stream)
{
    const float* x   = (const float*)d_in[0];
    const float* chi = (const float*)d_in[1];
    // d_in[2] = z_one_hot : unused
    const float* W1  = (const float*)d_in[3];
    const float* b1  = (const float*)d_in[4];
    const float* W2  = (const float*)d_in[5];
    const float* W3  = (const float*)d_in[6];
    const float* W4  = (const float*)d_in[7];
    const float* b4  = (const float*)d_in[8];

    char* ws = (char*)d_ws;
    bf16_t* W1b  = (bf16_t*)(ws + 0);
    bf16_t* W2t  = (bf16_t*)(ws + 524288);
    bf16_t* W4t  = (bf16_t*)(ws + 1048576);
    bf16_t* Wct  = (bf16_t*)(ws + 2621440);
    float*  bc   = (float*) (ws + 3145728);
    float*  u    = (float*) (ws + 3147776);
    bf16_t* A3   = (bf16_t*)(ws + 3149824);
    float*  Wctp = (float*) (ws + 3149824);   // overlaps A3 head; dead before A3 written

    float*  xbo  = (float*)d_out;                          // 24576*512 f32
    float*  chbo = (float*)d_out + (size_t)NNODES * 512;   // 24576*15 f32
    char*   c0s  = (char*)d_out;
    float*  c3   = (float*) (c0s + 25165824);
    float*  sbuf = (float*) (c0s + 25460736);

    // prep
    prep_kernel<<<4224, 256, 0, stream>>>(W1, W1b, W2, W2t, W4, W4t);
    vecmat_kernel<<<2, 256, 0, stream>>>(b1, W1, u);
    vecmat_kernel<<<2, 256, 0, stream>>>(u, W2, bc);
    c3_kernel<<<96, 256, 0, stream>>>(chi, c3, sbuf);

    // Wct = (W1@W2)^T via split-K partials + reduce
    gemm8_kernel<<<dim3(2, 2, 4), 512, 0, stream>>>(W2t, W1b, Wctp, 512, 128, 512);
    wct_reduce_kernel<<<1024, 256, 0, stream>>>(Wctp, Wct);

    // G-GEMM (consumes f32 x directly): A3 = c_l * g^2 (coalesced) ; sbuf += g.W3
    gemm16x_kernel<<<dim3(128, 2), 1024, 0, stream>>>(x, Wct, bc, A3, W3, c3, sbuf);

    // chi_bo = chi * s
    chbo_kernel<<<1440, 256, 0, stream>>>(chi, sbuf, chbo);

    // x_bo = silu(A3 @ W4 + b4)
    gemm16_kernel<<<dim3(128, 2), 1024, 0, stream>>>(A3, W4t, b4, xbo, 512, 1536, 1);
}

// Round 17
// 139.138 us; speedup vs baseline: 1.2642x; 1.1165x over previous
//
#include <hip/hip_runtime.h>

typedef __bf16 bf16_t;
typedef __bf16 bf16x8 __attribute__((ext_vector_type(8)));
typedef __bf16 bf16x4 __attribute__((ext_vector_type(4)));
typedef float f32x4 __attribute__((ext_vector_type(4)));

#define BK 64
#define NNODES 24576

// ws layout (bytes):
//   0        W1b   (512*512 bf16)  = 524288
//   1048576  W4t   (512*1536 bf16) = 1572864
//   2621440  Wct   (512*512 bf16)  = 524288
//   3145728  bc    (512 f32)       = 2048
//   3147776  W2t   (512*512 bf16)  = 524288
//   3674112  A3    (24576*1536 bf16) = 75497472  [Wctp (4MB f32) overlaps A3
//            head: consumed by wct_reduce BEFORE gemm16x writes A3]
// d_out chunk0 (48MB f32 xbo, dead until final GEMM):
//   25165824 c3    (3*24576 f32)   = 294912
//   25460736 sbuf  (24576 f32)     = 98304

__device__ __forceinline__ void g2l16(const void* g, void* l) {
    __builtin_amdgcn_global_load_lds((__attribute__((address_space(1))) void*)(g),
                                     (__attribute__((address_space(3))) void*)(l),
                                     16, 0, 0);
}

#define SB()  __builtin_amdgcn_sched_barrier(0)
#define BAR() __builtin_amdgcn_s_barrier()

// ============ G-GEMM: A = f32 x consumed directly (fused cast) ============
__global__ __launch_bounds__(1024)
void gemm16x_kernel(const float* __restrict__ X, const bf16_t* __restrict__ Bt,
                    const float* __restrict__ bias, bf16_t* __restrict__ A3,
                    const float* __restrict__ W3, const float* __restrict__ c3v,
                    float* __restrict__ sbuf)
{
    __shared__ __align__(16) char smem[114688];
    char* baseA = smem;            // 2 x 24576 (192 rows x 128B per buf)
    char* baseB = smem + 49152;    // 2 x 32768 (256 rows x 128B per buf)

    const int tid  = threadIdx.x;
    const int lane = tid & 63;
    const int wave = tid >> 6;       // 0..15
    const int wr   = wave >> 2;
    const int wc   = wave & 3;
    const int l15  = lane & 15;
    const int lh   = lane >> 4;

    const int bm = blockIdx.x;
    const int bn = blockIdx.y;

    const size_t strbB = 1024;       // Wct row = 512 bf16

    const int q0 = tid * 16;
    const size_t roB = (size_t)(q0 >> 7) * strbB + ((q0 ^ (((q0 >> 7) & 7) << 4)) & 127);
    const char* gB = (const char*)Bt + (size_t)bn * 256 * strbB + roB;

    auto stageB = [&](int t, int buf) {
        const size_t kb = (size_t)t * 128;
        g2l16(gB + kb,                baseB + buf * 32768 + q0);
        g2l16(gB + kb + 128 * strbB,  baseB + buf * 32768 + 16384 + q0);
    };

    // A reg-stage: round r covers rows r*64..r*64+63
    const int arow0 = tid >> 4;              // 0..63
    const int e4    = (tid & 15) * 4;        // f32 col 0..60
    const float* gx = X + (size_t)(bm * 192 + arow0) * 512 + e4;
    const int woff0 = ((arow0 * 128) + e4 * 2) ^ ((arow0 & 7) << 4);

    float4 fA[3];
    auto loadA = [&](int t) {
#pragma unroll
        for (int r = 0; r < 3; ++r)
            fA[r] = *(const float4*)(gx + (size_t)r * 64 * 512 + t * 64);
    };
    auto writeA = [&](int buf) {
        char* d = baseA + buf * 24576;
#pragma unroll
        for (int r = 0; r < 3; ++r) {
            bf16x4 o;
            o[0] = (bf16_t)fA[r].x; o[1] = (bf16_t)fA[r].y;
            o[2] = (bf16_t)fA[r].z; o[3] = (bf16_t)fA[r].w;
            *(bf16x4*)(d + r * 8192 + woff0) = o;
        }
    };

    const int swzr = (l15 & 7) << 4;
    const int xk0  = (lh * 16) ^ swzr;
    const int xk1  = (64 + lh * 16) ^ swzr;
    const int aOff = (wr * 48 + l15) * 128;
    const int bOff = (wc * 64 + l15) * 128;

    f32x4 acc[3][4] = {};

    loadA(0); stageB(0, 0);
    asm volatile("s_waitcnt vmcnt(2)" ::: "memory");
    writeA(0);

    for (int t = 0; t < 8; ++t) {
        const int buf = t & 1;

        asm volatile("s_waitcnt vmcnt(0) lgkmcnt(0)" ::: "memory");
        BAR();
        SB();

        if (t < 7) { loadA(t + 1); stageB(t + 1, buf ^ 1); }
        SB();

        bf16x8 af[3][2], bf[4][2];
        {
            const char* _pa = baseA + buf * 24576 + aOff;
#pragma unroll
            for (int m = 0; m < 3; ++m) {
                af[m][0] = *(const bf16x8*)(_pa + m * 2048 + xk0);
                af[m][1] = *(const bf16x8*)(_pa + m * 2048 + xk1);
            }
            const char* _pb = baseB + buf * 32768 + bOff;
#pragma unroll
            for (int n = 0; n < 4; ++n) {
                bf[n][0] = *(const bf16x8*)(_pb + n * 2048 + xk0);
                bf[n][1] = *(const bf16x8*)(_pb + n * 2048 + xk1);
            }
        }

        __builtin_amdgcn_s_setprio(1);
#pragma unroll
        for (int m = 0; m < 3; ++m)
#pragma unroll
        for (int n = 0; n < 4; ++n)
#pragma unroll
        for (int kk = 0; kk < 2; ++kk)
            acc[m][n] = __builtin_amdgcn_mfma_f32_16x16x32_bf16(
                af[m][kk], bf[n][kk], acc[m][n], 0, 0, 0);
        __builtin_amdgcn_s_setprio(0);

        if (t < 7) {
            asm volatile("s_waitcnt vmcnt(2)" ::: "memory");
            SB();
            writeA(buf ^ 1);
        }
        SB();
    }

    // ---- epilogue ----
    BAR();
    bf16_t* sg = (bf16_t*)smem;
    const int gr0 = bm * 192 + wr * 48 + lh * 4;
    const int gc0 = bn * 256 + wc * 64 + l15;
    const int lr0 = wr * 48 + lh * 4;
    const int lc0 = wc * 64 + l15;
    float w3v[4], bv[4];
#pragma unroll
    for (int n = 0; n < 4; ++n) {
        w3v[n] = W3[gc0 + n * 16];
        bv[n]  = bias[gc0 + n * 16];
    }
#pragma unroll
    for (int m = 0; m < 3; ++m)
#pragma unroll
    for (int j = 0; j < 4; ++j) {
        const int r = gr0 + m * 16 + j;
        float g[4], p = 0.f;
#pragma unroll
        for (int n = 0; n < 4; ++n) {
            g[n] = acc[m][n][j] + bv[n];
            p += g[n] * w3v[n];
        }
        p += __shfl_xor(p, 1); p += __shfl_xor(p, 2);
        p += __shfl_xor(p, 4); p += __shfl_xor(p, 8);
        if (l15 == 0) atomicAdd(&sbuf[r], p);
        bf16_t* srow = sg + (lr0 + m * 16 + j) * 264 + lc0;
#pragma unroll
        for (int n = 0; n < 4; ++n)
            srow[n * 16] = (bf16_t)(g[n] * g[n]);
    }
    BAR();
    const int rl = tid >> 5;
    const int cb = (tid & 31) * 8;
#pragma unroll
    for (int pass = 0; pass < 6; ++pass) {
        const int row = pass * 32 + rl;
        const bf16x8 v = *(const bf16x8*)((const char*)sg + row * 528 + cb * 2);
        float f[8];
#pragma unroll
        for (int j = 0; j < 8; ++j) f[j] = (float)v[j];
        const int grow = bm * 192 + row;
#pragma unroll
        for (int l = 0; l < 3; ++l) {
            const float c = c3v[grow + l * NNODES];
            bf16x8 o;
#pragma unroll
            for (int j = 0; j < 8; ++j) o[j] = (bf16_t)(c * f[j]);
            *(bf16x8*)(A3 + (size_t)grow * 1536 + l * 512 + bn * 256 + cb) = o;
        }
    }
}

// ============ 16-wave GEMM (bf16 A) — final GEMM ============
__global__ __launch_bounds__(1024)
void gemm16_kernel(const bf16_t* __restrict__ A, const bf16_t* __restrict__ Bt,
                   const float* __restrict__ bias, void* __restrict__ Cout,
                   int N, int K, int mode)
{
    __shared__ __align__(16) bf16_t lA[2][12288];
    __shared__ __align__(16) bf16_t lB[2][16384];

    const int tid  = threadIdx.x;
    const int lane = tid & 63;
    const int wave = tid >> 6;
    const int wr   = wave >> 2;
    const int wc   = wave & 3;
    const int l15  = lane & 15;
    const int lh   = lane >> 4;

    const int bm = blockIdx.x;
    const int bn = blockIdx.y;

    const size_t strb = (size_t)K * 2;

    const int q0 = tid * 16;
    const size_t ro = (size_t)(q0 >> 7) * strb + ((q0 ^ (((q0 >> 7) & 7) << 4)) & 127);
    const char* gA = (const char*)A  + (size_t)bm * 192 * strb + ro;
    const char* gB = (const char*)Bt + (size_t)bn * 256 * strb + ro;
    char* baseA = (char*)&lA[0][0];
    char* baseB = (char*)&lB[0][0];

    auto stage = [&](int t, int buf) {
        const size_t kb = (size_t)t * 128;
        g2l16(gA + kb, baseA + buf * 24576 + q0);
        if (tid < 512)
            g2l16(gA + kb + 128 * strb, baseA + buf * 24576 + 16384 + q0);
        g2l16(gB + kb, baseB + buf * 32768 + q0);
        g2l16(gB + kb + 128 * strb, baseB + buf * 32768 + 16384 + q0);
    };

    const int swzr = (l15 & 7) << 4;
    const int xk0  = (lh * 16) ^ swzr;
    const int xk1  = (64 + lh * 16) ^ swzr;
    const int aOff = (wr * 48 + l15) * 128;
    const int bOff = (wc * 64 + l15) * 128;

    f32x4 acc[3][4] = {};

    const int T = K / BK;
    stage(0, 0);

    for (int t = 0; t < T; ++t) {
        const int buf = t & 1;

        asm volatile("s_waitcnt vmcnt(0)" ::: "memory");
        BAR();
        SB();

        if (t + 1 < T) stage(t + 1, buf ^ 1);
        SB();

        bf16x8 af[3][2], bf[4][2];
        {
            const char* _pa = baseA + buf * 24576 + aOff;
#pragma unroll
            for (int m = 0; m < 3; ++m) {
                af[m][0] = *(const bf16x8*)(_pa + m * 2048 + xk0);
                af[m][1] = *(const bf16x8*)(_pa + m * 2048 + xk1);
            }
            const char* _pb = baseB + buf * 32768 + bOff;
#pragma unroll
            for (int n = 0; n < 4; ++n) {
                bf[n][0] = *(const bf16x8*)(_pb + n * 2048 + xk0);
                bf[n][1] = *(const bf16x8*)(_pb + n * 2048 + xk1);
            }
        }

        __builtin_amdgcn_s_setprio(1);
#pragma unroll
        for (int m = 0; m < 3; ++m)
#pragma unroll
        for (int n = 0; n < 4; ++n)
#pragma unroll
        for (int kk = 0; kk < 2; ++kk)
            acc[m][n] = __builtin_amdgcn_mfma_f32_16x16x32_bf16(
                af[m][kk], bf[n][kk], acc[m][n], 0, 0, 0);
        __builtin_amdgcn_s_setprio(0);
    }

    const int gr0 = bm * 192 + wr * 48 + lh * 4;
    const int gc0 = bn * 256 + wc * 64 + l15;
    if (mode == 0) {
        bf16_t* C = (bf16_t*)Cout;
#pragma unroll
        for (int m = 0; m < 3; ++m)
#pragma unroll
        for (int n = 0; n < 4; ++n) {
            const int c = gc0 + n * 16;
            const float bv = bias ? bias[c] : 0.f;
#pragma unroll
            for (int j = 0; j < 4; ++j)
                C[(size_t)(gr0 + m * 16 + j) * N + c] = (bf16_t)(acc[m][n][j] + bv);
        }
    } else {
        float* C = (float*)Cout;
#pragma unroll
        for (int m = 0; m < 3; ++m)
#pragma unroll
        for (int n = 0; n < 4; ++n) {
            const int c = gc0 + n * 16;
            const float bv = bias[c];
#pragma unroll
            for (int j = 0; j < 4; ++j) {
                float v = acc[m][n][j] + bv;
                C[(size_t)(gr0 + m * 16 + j) * N + c] = v / (1.f + __expf(-v));
            }
        }
    }
}

// ============ 8-wave GEMM (split-K) — Wct partials only ============
__global__ __launch_bounds__(512)
void gemm8_kernel(const bf16_t* __restrict__ A, const bf16_t* __restrict__ Bt,
                  void* __restrict__ Cout, int N, int K, int LD)
{
    __shared__ __align__(16) bf16_t lA[2][16384];
    __shared__ __align__(16) bf16_t lB[2][16384];

    const int tid  = threadIdx.x;
    const int lane = tid & 63;
    const int wave = tid >> 6;
    const int wr   = wave >> 2;
    const int wc   = wave & 3;
    const int l15  = lane & 15;
    const int lh   = lane >> 4;

    const int bm = blockIdx.x;
    const int bn = blockIdx.y;
    const int bz = blockIdx.z;

    const size_t strb = (size_t)LD * 2;
    const size_t zoff = (size_t)bz * K * 2;

    const int q0 = tid * 16;
    const size_t rowOff = (size_t)(q0 >> 7) * strb + ((q0 ^ (((q0 >> 7) & 7) << 4)) & 127);
    const char* gA = (const char*)A  + (size_t)bm * 256 * strb + zoff + rowOff;
    const char* gB = (const char*)Bt + (size_t)bn * 256 * strb + zoff + rowOff;
    char* baseA = (char*)&lA[0][0];
    char* baseB = (char*)&lB[0][0];

    auto stageA = [&](int t, int buf, int r) {
        g2l16(gA + (size_t)t * 128 + (size_t)(r * 64) * strb,
              baseA + buf * 32768 + r * 8192 + q0);
    };
    auto stageB = [&](int t, int buf, int r) {
        g2l16(gB + (size_t)t * 128 + (size_t)(r * 64) * strb,
              baseB + buf * 32768 + r * 8192 + q0);
    };

    const int swzr = (l15 & 7) << 4;
    const int xk0  = (lh * 16) ^ swzr;
    const int xk1  = (64 + lh * 16) ^ swzr;
    const int aOff = wr * 16384 + l15 * 128;
    const int bOff = wc * 8192 + l15 * 128;

    f32x4 acc[2][2][4][2] = {};

    const int T = K / BK;

#pragma unroll
    for (int r = 0; r < 4; ++r) { stageA(0, 0, r); stageB(0, 0, r); }

    for (int t = 0; t < T; ++t) {
        const int buf = t & 1, nbuf = buf ^ 1;

        asm volatile("s_waitcnt vmcnt(0)" ::: "memory");
        BAR();
        SB();

        if (t + 1 < T) {
#pragma unroll
            for (int r = 0; r < 4; ++r) { stageA(t + 1, nbuf, r); stageB(t + 1, nbuf, r); }
        }
        SB();

        bf16x8 af[8][2], bf[4][2];
        {
            const char* _pa = baseA + buf * 32768 + aOff;
#pragma unroll
            for (int i = 0; i < 8; ++i) {
                af[i][0] = *(const bf16x8*)(_pa + i * 2048 + xk0);
                af[i][1] = *(const bf16x8*)(_pa + i * 2048 + xk1);
            }
            const char* _pb = baseB + buf * 32768 + bOff;
#pragma unroll
            for (int j = 0; j < 4; ++j) {
                bf[j][0] = *(const bf16x8*)(_pb + j * 2048 + xk0);
                bf[j][1] = *(const bf16x8*)(_pb + j * 2048 + xk1);
            }
        }

        __builtin_amdgcn_s_setprio(1);
#pragma unroll
        for (int mh = 0; mh < 2; ++mh)
#pragma unroll
        for (int nh = 0; nh < 2; ++nh)
#pragma unroll
        for (int m = 0; m < 4; ++m)
#pragma unroll
        for (int n = 0; n < 2; ++n)
#pragma unroll
        for (int kk = 0; kk < 2; ++kk)
            acc[mh][nh][m][n] = __builtin_amdgcn_mfma_f32_16x16x32_bf16(
                af[mh * 4 + m][kk], bf[nh * 2 + n][kk], acc[mh][nh][m][n], 0, 0, 0);
        __builtin_amdgcn_s_setprio(0);
    }

    float* C = (float*)Cout + (size_t)bz * 512 * 512;
    const int gr0 = bm * 256 + wr * 128 + lh * 4;
    const int gc0 = bn * 256 + wc * 64 + l15;
#pragma unroll
    for (int mh = 0; mh < 2; ++mh)
#pragma unroll
    for (int nh = 0; nh < 2; ++nh)
#pragma unroll
    for (int m = 0; m < 4; ++m)
#pragma unroll
    for (int n = 0; n < 2; ++n) {
        const int c = gc0 + nh * 32 + n * 16;
#pragma unroll
        for (int j = 0; j < 4; ++j)
            C[(size_t)(gr0 + (mh * 4 + m) * 16 + j) * N + c] = acc[mh][nh][m][n][j];
    }
}

__global__ void wct_reduce_kernel(const float* __restrict__ p, bf16_t* __restrict__ out) {
    const int i = blockIdx.x * 256 + threadIdx.x;   // < 262144
    out[i] = (bf16_t)(p[i] + p[i + 262144] + p[i + 524288] + p[i + 786432]);
}

// W1 f32 -> bf16 cast (coalesced)
__global__ void prepw1_kernel(const float* __restrict__ W1, bf16_t* __restrict__ W1b) {
    const int i = blockIdx.x * 256 + threadIdx.x;
    const float4* p = (const float4*)W1 + (size_t)i * 2;
    float4 a = p[0], c = p[1];
    bf16x8 v;
    v[0] = (bf16_t)a.x; v[1] = (bf16_t)a.y; v[2] = (bf16_t)a.z; v[3] = (bf16_t)a.w;
    v[4] = (bf16_t)c.x; v[5] = (bf16_t)c.y; v[6] = (bf16_t)c.z; v[7] = (bf16_t)c.w;
    *(bf16x8*)(W1b + (size_t)i * 8) = v;
}

// LDS-tiled transpose+cast: in is R rows x C cols; out[c*R + r] = bf16(in[r*C + c]).
// Launch: grid (C/64, R/64). 64x64 tiles, pad-65 conflict-free LDS.
__global__ __launch_bounds__(256)
void tr_kernel(const float* __restrict__ in, bf16_t* __restrict__ out, int R, int C) {
    __shared__ float tile[64][65];
    const int c0 = blockIdx.x * 64, r0 = blockIdx.y * 64;
    const int tx = threadIdx.x & 63, ty = threadIdx.x >> 6;   // ty 0..3
#pragma unroll
    for (int p = 0; p < 16; ++p) {
        const int r = p * 4 + ty;
        tile[r][tx] = in[(size_t)(r0 + r) * C + c0 + tx];
    }
    __syncthreads();
#pragma unroll
    for (int p = 0; p < 16; ++p) {
        const int c = p * 4 + ty;
        out[(size_t)(c0 + c) * R + r0 + tx] = (bf16_t)tile[tx][c];
    }
}

// bc[t] = sum_i b1[i] * W2[i][t]   (G = x@(W1W2) + b1@W2)
__global__ void vecmat_kernel(const float* __restrict__ v, const float* __restrict__ W,
                              float* __restrict__ out) {
    const int t = blockIdx.x * blockDim.x + threadIdx.x;
    if (t >= 512) return;
    float s = 0.f;
    for (int i = 0; i < 512; ++i) s += v[i] * W[i * 512 + t];
    out[t] = s;
}

// c3[l][n] = sum_{m in seg l} chi[n,m]^2 ; also zeroes sbuf (replay-safe)
__global__ void c3_kernel(const float* __restrict__ chi, float* __restrict__ c3,
                          float* __restrict__ sbuf) {
    const int n = blockIdx.x * 256 + threadIdx.x;
    if (n >= NNODES) return;
    const float* ch = chi + (size_t)n * 15;
    float a = 0.f, b = 0.f, c = 0.f;
#pragma unroll
    for (int m = 0; m < 3; ++m)  a += ch[m] * ch[m];
#pragma unroll
    for (int m = 3; m < 8; ++m)  b += ch[m] * ch[m];
#pragma unroll
    for (int m = 8; m < 15; ++m) c += ch[m] * ch[m];
    c3[n] = a; c3[n + NNODES] = b; c3[n + 2 * NNODES] = c;
    sbuf[n] = 0.f;
}

// chbo[n,m] = chi[n,m] * s[n]
__global__ void chbo_kernel(const float* __restrict__ chi, const float* __restrict__ s,
                            float* __restrict__ chbo) {
    const int idx = blockIdx.x * 256 + threadIdx.x;
    if (idx >= NNODES * 15) return;
    chbo[idx] = chi[idx] * s[idx / 15];
}

extern "C" void kernel_launch(void* const* d_in, const int* in_sizes, int n_in,
                              void* d_out, int out_size, void* d_ws, size_t ws_size,
                              hipStream_t stream)
{
    const float* x   = (const float*)d_in[0];
    const float* chi = (const float*)d_in[1];
    // d_in[2] = z_one_hot : unused
    const float* W1  = (const float*)d_in[3];
    const float* b1  = (const float*)d_in[4];
    const float* W2  = (const float*)d_in[5];
    const float* W3  = (const float*)d_in[6];
    const float* W4  = (const float*)d_in[7];
    const float* b4  = (const float*)d_in[8];

    char* ws = (char*)d_ws;
    bf16_t* W1b  = (bf16_t*)(ws + 0);
    bf16_t* W4t  = (bf16_t*)(ws + 1048576);
    bf16_t* Wct  = (bf16_t*)(ws + 2621440);
    float*  bc   = (float*) (ws + 3145728);
    bf16_t* W2t  = (bf16_t*)(ws + 3147776);
    bf16_t* A3   = (bf16_t*)(ws + 3674112);
    float*  Wctp = (float*) (ws + 3674112);   // overlaps A3 head; dead before A3 written

    float*  xbo  = (float*)d_out;                          // 24576*512 f32
    float*  chbo = (float*)d_out + (size_t)NNODES * 512;   // 24576*15 f32
    char*   c0s  = (char*)d_out;
    float*  c3   = (float*) (c0s + 25165824);
    float*  sbuf = (float*) (c0s + 25460736);

    // prep (coalesced)
    prepw1_kernel<<<128, 256, 0, stream>>>(W1, W1b);
    tr_kernel<<<dim3(8, 8),  256, 0, stream>>>(W2, W2t, 512, 512);    // W2: 512x512
    tr_kernel<<<dim3(8, 24), 256, 0, stream>>>(W4, W4t, 1536, 512);   // W4: 1536x512 (FIXED)
    vecmat_kernel<<<2, 256, 0, stream>>>(b1, W2, bc);      // bc = b1 @ W2
    c3_kernel<<<96, 256, 0, stream>>>(chi, c3, sbuf);

    // Wct = (W1@W2)^T via split-K partials + reduce
    gemm8_kernel<<<dim3(2, 2, 4), 512, 0, stream>>>(W2t, W1b, Wctp, 512, 128, 512);
    wct_reduce_kernel<<<1024, 256, 0, stream>>>(Wctp, Wct);

    // G-GEMM (consumes f32 x directly): A3 = c_l * g^2 (coalesced) ; sbuf += g.W3
    gemm16x_kernel<<<dim3(128, 2), 1024, 0, stream>>>(x, Wct, bc, A3, W3, c3, sbuf);

    // chi_bo = chi * s
    chbo_kernel<<<1440, 256, 0, stream>>>(chi, sbuf, chbo);

    // x_bo = silu(A3 @ W4 + b4)
    gemm16_kernel<<<dim3(128, 2), 1024, 0, stream>>>(A3, W4t, b4, xbo, 512, 1536, 1);
}